// Round 2
// baseline (610.754 us; speedup 1.0000x reference)
//
#include <hip/hip_runtime.h>
#include <hip/hip_bf16.h>

typedef __bf16 bf16;
typedef __bf16 bf16x4 __attribute__((ext_vector_type(4)));
typedef __bf16 bf16x8 __attribute__((ext_vector_type(8)));
typedef float f32x4 __attribute__((ext_vector_type(4)));

__device__ __forceinline__ void gload_lds16(const void* g, void* l) {
  __builtin_amdgcn_global_load_lds((__attribute__((address_space(1))) void*)(g),
                                   (__attribute__((address_space(3))) void*)(l), 16, 0, 0);
}

// ---------------- diagnostic: encode ws_size into output if workspace too small ----
__global__ void k_diag(float* __restrict__ o, float v) { o[threadIdx.x] = v; }

// ---------------- fp32 -> bf16 convert (vectorized) ----------------
__global__ void k_cvt_bf16(const float* __restrict__ x, bf16* __restrict__ y, int n4) {
  int i = blockIdx.x * blockDim.x + threadIdx.x;
  if (i < n4) {
    float4 v = reinterpret_cast<const float4*>(x)[i];
    bf16x4 o = {(bf16)v.x, (bf16)v.y, (bf16)v.z, (bf16)v.w};
    reinterpret_cast<bf16x4*>(y)[i] = o;
  }
}

// ---------------- W (K x N fp32, row-major) -> Wt (N x K bf16) ----------------
__global__ void k_transpose_w(const float* __restrict__ W, bf16* __restrict__ Wt, int K, int N) {
  __shared__ float tile[32][33];
  int kb = blockIdx.x * 32, nb = blockIdx.y * 32;
  int tx = threadIdx.x & 31, ty = threadIdx.x >> 5;  // 8 rows per pass
#pragma unroll
  for (int i = 0; i < 32; i += 8)
    tile[ty + i][tx] = W[(size_t)(kb + ty + i) * N + nb + tx];
  __syncthreads();
#pragma unroll
  for (int i = 0; i < 32; i += 8)
    Wt[(size_t)(nb + ty + i) * K + kb + tx] = (bf16)tile[tx][ty + i];
}

// ---------------- 128x128 bf16 GEMM: C[M,N] = A[M,K] * Bt[N,K]^T ----------------
template <typename OT>
__global__ __launch_bounds__(256) void k_gemm(const bf16* __restrict__ A, const bf16* __restrict__ Bt,
                                              OT* __restrict__ C, int M, int N, int Kd) {
  __shared__ __align__(16) bf16 sA[128 * 32];
  __shared__ __align__(16) bf16 sB[128 * 32];
  const int t = threadIdx.x;
  const int w = t >> 6, l = t & 63;
  const int lr = l & 15, lk = l >> 4;
  const int m0 = blockIdx.x * 128, n0 = blockIdx.y * 128;
  const int wm = (w >> 1) * 64, wn = (w & 1) * 64;
  const bf16* ga = A + (size_t)(m0 + (t >> 2)) * Kd + (t & 3) * 8;
  const bf16* gb = Bt + (size_t)(n0 + (t >> 2)) * Kd + (t & 3) * 8;
  bf16* lA = sA + w * 512;  // wave-uniform LDS base (bytes w*1024)
  bf16* lB = sB + w * 512;
  const size_t rowskip = (size_t)64 * Kd;
  f32x4 acc[4][4] = {};
  for (int k0 = 0; k0 < Kd; k0 += 32) {
    __syncthreads();
    gload_lds16(ga + k0, lA);
    gload_lds16(ga + rowskip + k0, lA + 2048);
    gload_lds16(gb + k0, lB);
    gload_lds16(gb + rowskip + k0, lB + 2048);
    __syncthreads();
    bf16x8 af[4], bfr[4];
#pragma unroll
    for (int i = 0; i < 4; ++i)
      af[i] = *reinterpret_cast<const bf16x8*>(sA + (wm + i * 16 + lr) * 32 + lk * 8);
#pragma unroll
    for (int j = 0; j < 4; ++j)
      bfr[j] = *reinterpret_cast<const bf16x8*>(sB + (wn + j * 16 + lr) * 32 + lk * 8);
#pragma unroll
    for (int i = 0; i < 4; ++i)
#pragma unroll
      for (int j = 0; j < 4; ++j)
        acc[i][j] = __builtin_amdgcn_mfma_f32_16x16x32_bf16(af[i], bfr[j], acc[i][j], 0, 0, 0);
  }
#pragma unroll
  for (int i = 0; i < 4; ++i)
#pragma unroll
    for (int j = 0; j < 4; ++j)
#pragma unroll
      for (int r = 0; r < 4; ++r) {
        int row = m0 + wm + i * 16 + lk * 4 + r;
        int col = n0 + wn + j * 16 + lr;
        if constexpr (sizeof(OT) == 4)
          C[(size_t)row * N + col] = acc[i][j][r];
        else
          C[(size_t)row * N + col] = (bf16)acc[i][j][r];
      }
}

// ---------------- RoPE in place (optionally folds softmax scale) ----------------
__global__ void k_rope(bf16* __restrict__ X, const float* __restrict__ cs, const float* __restrict__ sn,
                       int nh, int rowstride, float scale, int total) {
  int idx = blockIdx.x * blockDim.x + threadIdx.x;
  if (idx >= total) return;
  int d = idx & 63;
  int th = idx >> 6;
  int h = th % nh;
  int tok = th / nh;
  size_t base = (size_t)tok * rowstride + h * 128;
  float c = cs[tok * 128 + d], s = sn[tok * 128 + d];
  float x1 = (float)X[base + d];
  float x2 = (float)X[base + d + 64];
  X[base + d] = (bf16)((x1 * c - x2 * s) * scale);
  X[base + d + 64] = (bf16)((x2 * c + x1 * s) * scale);
}

// ---------------- causal flash attention, GQA 4:1, bf16 MFMA ----------------
// grid: (S/64, NH, B); 256 threads = 4 waves; wave w owns q rows [qt*64+16w, +16)
__global__ __launch_bounds__(256) void k_attn(const bf16* __restrict__ Q, const bf16* __restrict__ KV,
                                              bf16* __restrict__ O) {
  constexpr int S = 2048, NH = 16, HD = 128, QSTR = NH * HD, KVSTR = 1024;
  __shared__ __align__(16) bf16 sK[32][136];   // [kv][d], padded rows (272B) to spread banks
  __shared__ __align__(16) bf16 sV[128][40];   // [d][kv] transposed, padded (80B rows)
  __shared__ __align__(16) bf16 sP[4][16][40]; // per-wave P redistribution buffer
  const int qt = blockIdx.x, h = blockIdx.y, b = blockIdx.z;
  const int t = threadIdx.x, w = t >> 6, l = t & 63;
  const int lr = l & 15, lk = l >> 4;
  const int kvh = h >> 2;
  const int qbase = qt * 64;
  const int qw = qbase + w * 16;
  const bf16* Qp = Q + (size_t)(b * S + qw + lr) * QSTR + h * HD + lk * 8;
  bf16x8 qf[4];
#pragma unroll
  for (int i = 0; i < 4; ++i) qf[i] = *reinterpret_cast<const bf16x8*>(Qp + i * 32);
  f32x4 oacc[8] = {};
  float mrow[4] = {-1e30f, -1e30f, -1e30f, -1e30f};
  float lsum[4] = {0.f, 0.f, 0.f, 0.f};
  const bf16* Kb = KV + (size_t)b * S * KVSTR + kvh * HD;
  const bf16* Vb = Kb + 512;
  const int ntiles = (qbase + 64) >> 5;
  for (int tt = 0; tt < ntiles; ++tt) {
    const int kvb = tt * 32;
    __syncthreads();  // all waves done reading previous tile's LDS
#pragma unroll
    for (int i = 0; i < 2; ++i) {
      int t2 = i * 256 + t;
      int row = t2 >> 4, dd = (t2 & 15) * 8;
      const size_t goff = (size_t)(kvb + row) * KVSTR + dd;
      *reinterpret_cast<bf16x8*>(&sK[row][dd]) = *reinterpret_cast<const bf16x8*>(Kb + goff);
      bf16x8 vv = *reinterpret_cast<const bf16x8*>(Vb + goff);
#pragma unroll
      for (int j = 0; j < 8; ++j) sV[dd + j][row] = vv[j];
    }
    __syncthreads();
    // QK^T: 16x32 scores per wave (Q pre-scaled by 1/sqrt(HD))
    f32x4 sc[2];
#pragma unroll
    for (int c = 0; c < 2; ++c) {
      f32x4 s4 = {};
#pragma unroll
      for (int kf = 0; kf < 4; ++kf) {
        bf16x8 kf8 = *reinterpret_cast<const bf16x8*>(&sK[c * 16 + lr][kf * 32 + lk * 8]);
        s4 = __builtin_amdgcn_mfma_f32_16x16x32_bf16(qf[kf], kf8, s4, 0, 0, 0);
      }
      sc[c] = s4;
    }
    // causal mask + online softmax
    float pm[2][4];
#pragma unroll
    for (int c = 0; c < 2; ++c)
#pragma unroll
      for (int r = 0; r < 4; ++r) {
        int col = kvb + c * 16 + lr;
        int row = qw + lk * 4 + r;
        pm[c][r] = (col > row) ? -1e30f : sc[c][r];
      }
    float mx[4];
#pragma unroll
    for (int r = 0; r < 4; ++r) mx[r] = fmaxf(pm[0][r], pm[1][r]);
#pragma unroll
    for (int off = 1; off < 16; off <<= 1)
#pragma unroll
      for (int r = 0; r < 4; ++r) mx[r] = fmaxf(mx[r], __shfl_xor(mx[r], off));
    float fac[4], rs[4];
#pragma unroll
    for (int r = 0; r < 4; ++r) {
      float mn = fmaxf(mrow[r], mx[r]);
      fac[r] = __expf(mrow[r] - mn);
      mrow[r] = mn;
    }
#pragma unroll
    for (int c = 0; c < 2; ++c)
#pragma unroll
      for (int r = 0; r < 4; ++r) pm[c][r] = __expf(pm[c][r] - mrow[r]);
#pragma unroll
    for (int r = 0; r < 4; ++r) rs[r] = pm[0][r] + pm[1][r];
#pragma unroll
    for (int off = 1; off < 16; off <<= 1)
#pragma unroll
      for (int r = 0; r < 4; ++r) rs[r] += __shfl_xor(rs[r], off);
#pragma unroll
    for (int r = 0; r < 4; ++r) lsum[r] = lsum[r] * fac[r] + rs[r];
#pragma unroll
    for (int ch = 0; ch < 8; ++ch)
#pragma unroll
      for (int r = 0; r < 4; ++r) oacc[ch][r] *= fac[r];
    // P: D-frag layout -> A-frag layout via per-wave LDS
#pragma unroll
    for (int c = 0; c < 2; ++c)
#pragma unroll
      for (int r = 0; r < 4; ++r) sP[w][lk * 4 + r][c * 16 + lr] = (bf16)pm[c][r];
    bf16x8 pf = *reinterpret_cast<const bf16x8*>(&sP[w][lr][lk * 8]);
#pragma unroll
    for (int ch = 0; ch < 8; ++ch) {
      bf16x8 vf = *reinterpret_cast<const bf16x8*>(&sV[ch * 16 + lr][lk * 8]);
      oacc[ch] = __builtin_amdgcn_mfma_f32_16x16x32_bf16(pf, vf, oacc[ch], 0, 0, 0);
    }
  }
  float inv[4];
#pragma unroll
  for (int r = 0; r < 4; ++r) inv[r] = 1.0f / lsum[r];
  bf16* Op = O + (size_t)(b * S + qw) * QSTR + h * HD;
#pragma unroll
  for (int ch = 0; ch < 8; ++ch)
#pragma unroll
    for (int r = 0; r < 4; ++r)
      Op[(size_t)(lk * 4 + r) * QSTR + ch * 16 + lr] = (bf16)(oacc[ch][r] * inv[r]);
}

extern "C" void kernel_launch(void* const* d_in, const int* in_sizes, int n_in,
                              void* d_out, int out_size, void* d_ws, size_t ws_size,
                              hipStream_t stream) {
  const float* hs = (const float*)d_in[0];
  // d_in[1] = attention_mask: pure causal, applied analytically
  const float* cosb = (const float*)d_in[2];
  const float* sinb = (const float*)d_in[3];
  const float* Wq = (const float*)d_in[4];
  const float* Wk = (const float*)d_in[5];
  const float* Wv = (const float*)d_in[6];
  const float* Wo = (const float*)d_in[7];
  float* out = (float*)d_out;

  constexpr int B = 2, S = 2048, H = 2048, NH = 16, NKV = 4, HD = 128;
  constexpr int T = B * S;  // 4096 tokens
  constexpr size_t MB = 1024 * 1024;

  // Workspace plan (24 MiB in d_ws; Q/KV staged inside d_out which is 32 MiB):
  //   d_ws[ 0:16M) : Xb (bf16 X), reused as Ob after QKV projections
  //   d_ws[16:24M) : transposed-weight slot: Wqt -> Wkvt -> Wot (serial lifetimes)
  //   d_out[ 0:16M): Qb (bf16)   -- dead before final GEMM overwrites d_out
  //   d_out[16:24M): KVb (bf16)  -- dead before final GEMM overwrites d_out
  const size_t ws_need = 24 * MB;
  if (ws_size < ws_need) {
    // Diagnostic: make absmax encode ws_size in MiB (absmax ~= 1000 + MiB).
    k_diag<<<1, 64, 0, stream>>>(out, 1000.0f + (float)(ws_size / MB));
    return;
  }
  bf16* Xb = (bf16*)d_ws;                      // 16 MiB, later Ob
  bf16* Wt = (bf16*)((char*)d_ws + 16 * MB);   // 8 MiB slot
  bf16* Ob = Xb;
  bf16* Qb = (bf16*)d_out;                     // 16 MiB
  bf16* KVb = (bf16*)((char*)d_out + 16 * MB); // 8 MiB

  k_cvt_bf16<<<T * H / 4 / 256, 256, 0, stream>>>(hs, Xb, T * H / 4);

  // Q projection
  k_transpose_w<<<dim3(H / 32, NH * HD / 32), 256, 0, stream>>>(Wq, Wt, H, NH * HD);
  k_gemm<bf16><<<dim3(T / 128, NH * HD / 128), 256, 0, stream>>>(Xb, Wt, Qb, T, NH * HD, H);

  // K|V fused projection (rows 0..511 = K, 512..1023 = V in the N dim)
  k_transpose_w<<<dim3(H / 32, NKV * HD / 32), 256, 0, stream>>>(Wk, Wt, H, NKV * HD);
  k_transpose_w<<<dim3(H / 32, NKV * HD / 32), 256, 0, stream>>>(Wv, Wt + (size_t)(NKV * HD) * H, H, NKV * HD);
  k_gemm<bf16><<<dim3(T / 128, 1024 / 128), 256, 0, stream>>>(Xb, Wt, KVb, T, 1024, H);

  // RoPE (fold 1/sqrt(HD) into Q)
  const float qscale = 0.08838834764831845f;
  k_rope<<<(T * NH * 64) / 256, 256, 0, stream>>>(Qb, cosb, sinb, NH, NH * HD, qscale, T * NH * 64);
  k_rope<<<(T * NKV * 64) / 256, 256, 0, stream>>>(KVb, cosb, sinb, NKV, 1024, 1.0f, T * NKV * 64);

  // Attention: reads Q/KV from d_out, writes Ob into d_ws (Xb dead)
  k_attn<<<dim3(S / 64, NH, B), 256, 0, stream>>>(Qb, KVb, Ob);

  // O projection: reads only d_ws (Ob, Wot), writes all of d_out
  k_transpose_w<<<dim3(H / 32, H / 32), 256, 0, stream>>>(Wo, Wt, H, H);
  k_gemm<float><<<dim3(T / 128, H / 128), 256, 0, stream>>>(Ob, Wt, out, T, H, H);
}

// Round 3
// 289.584 us; speedup vs baseline: 2.1091x; 2.1091x over previous
//
#include <hip/hip_runtime.h>
#include <hip/hip_bf16.h>

typedef __bf16 bf16;
typedef __bf16 bf16x4 __attribute__((ext_vector_type(4)));
typedef __bf16 bf16x8 __attribute__((ext_vector_type(8)));
typedef float f32x4 __attribute__((ext_vector_type(4)));

__device__ __forceinline__ void gload_lds16(const void* g, void* l) {
  __builtin_amdgcn_global_load_lds((__attribute__((address_space(1))) void*)(g),
                                   (__attribute__((address_space(3))) void*)(l), 16, 0, 0);
}

// ---------------- diagnostic: encode ws_size into output if workspace too small ----
__global__ void k_diag(float* __restrict__ o, float v) { o[threadIdx.x] = v; }

// ---------------- fp32 -> bf16 convert (vectorized) ----------------
__global__ void k_cvt_bf16(const float* __restrict__ x, bf16* __restrict__ y, int n4) {
  int i = blockIdx.x * blockDim.x + threadIdx.x;
  if (i < n4) {
    float4 v = reinterpret_cast<const float4*>(x)[i];
    bf16x4 o = {(bf16)v.x, (bf16)v.y, (bf16)v.z, (bf16)v.w};
    reinterpret_cast<bf16x4*>(y)[i] = o;
  }
}

// ---------------- W (K x N fp32, row-major) -> Wt (N x K bf16) ----------------
__global__ void k_transpose_w(const float* __restrict__ W, bf16* __restrict__ Wt, int K, int N) {
  __shared__ float tile[32][33];
  int kb = blockIdx.x * 32, nb = blockIdx.y * 32;
  int tx = threadIdx.x & 31, ty = threadIdx.x >> 5;
#pragma unroll
  for (int i = 0; i < 32; i += 8)
    tile[ty + i][tx] = W[(size_t)(kb + ty + i) * N + nb + tx];
  __syncthreads();
#pragma unroll
  for (int i = 0; i < 32; i += 8)
    Wt[(size_t)(nb + ty + i) * K + kb + tx] = (bf16)tile[tx][ty + i];
}

// ---------------- V (cols 512..1023 of KVb) -> Vt[b][kvh][HD][S] (bf16) ----------------
__global__ void k_transpose_v(const bf16* __restrict__ KVb, bf16* __restrict__ Vt) {
  __shared__ bf16 tile[32][34];
  constexpr int S = 2048;
  int sb = blockIdx.x * 32, db = blockIdx.y * 32, bh = blockIdx.z;  // bh = b*4+kvh
  int b = bh >> 2, kvh = bh & 3;
  int tx = threadIdx.x & 31, ty = threadIdx.x >> 5;
  const bf16* src = KVb + (size_t)b * S * 1024 + 512 + kvh * 128;
#pragma unroll
  for (int i = 0; i < 32; i += 8)
    tile[ty + i][tx] = src[(size_t)(sb + ty + i) * 1024 + db + tx];
  __syncthreads();
  bf16* dst = Vt + (size_t)bh * 128 * S;
#pragma unroll
  for (int i = 0; i < 32; i += 8)
    dst[(size_t)(db + ty + i) * S + sb + tx] = tile[tx][ty + i];
}

// ---------------- 128x128 bf16 GEMM: C[M,N] = A[M,K] * Bt[N,K]^T ----------------
template <typename OT>
__global__ __launch_bounds__(256) void k_gemm(const bf16* __restrict__ A, const bf16* __restrict__ Bt,
                                              OT* __restrict__ C, int M, int N, int Kd) {
  __shared__ __align__(16) bf16 sA[128 * 32];
  __shared__ __align__(16) bf16 sB[128 * 32];
  const int t = threadIdx.x;
  const int w = t >> 6, l = t & 63;
  const int lr = l & 15, lk = l >> 4;
  const int m0 = blockIdx.x * 128, n0 = blockIdx.y * 128;
  const int wm = (w >> 1) * 64, wn = (w & 1) * 64;
  const bf16* ga = A + (size_t)(m0 + (t >> 2)) * Kd + (t & 3) * 8;
  const bf16* gb = Bt + (size_t)(n0 + (t >> 2)) * Kd + (t & 3) * 8;
  bf16* lA = sA + w * 512;
  bf16* lB = sB + w * 512;
  const size_t rowskip = (size_t)64 * Kd;
  f32x4 acc[4][4] = {};
  for (int k0 = 0; k0 < Kd; k0 += 32) {
    __syncthreads();
    gload_lds16(ga + k0, lA);
    gload_lds16(ga + rowskip + k0, lA + 2048);
    gload_lds16(gb + k0, lB);
    gload_lds16(gb + rowskip + k0, lB + 2048);
    __syncthreads();
    bf16x8 af[4], bfr[4];
#pragma unroll
    for (int i = 0; i < 4; ++i)
      af[i] = *reinterpret_cast<const bf16x8*>(sA + (wm + i * 16 + lr) * 32 + lk * 8);
#pragma unroll
    for (int j = 0; j < 4; ++j)
      bfr[j] = *reinterpret_cast<const bf16x8*>(sB + (wn + j * 16 + lr) * 32 + lk * 8);
#pragma unroll
    for (int i = 0; i < 4; ++i)
#pragma unroll
      for (int j = 0; j < 4; ++j)
        acc[i][j] = __builtin_amdgcn_mfma_f32_16x16x32_bf16(af[i], bfr[j], acc[i][j], 0, 0, 0);
  }
#pragma unroll
  for (int i = 0; i < 4; ++i)
#pragma unroll
    for (int j = 0; j < 4; ++j)
#pragma unroll
      for (int r = 0; r < 4; ++r) {
        int row = m0 + wm + i * 16 + lk * 4 + r;
        int col = n0 + wn + j * 16 + lr;
        if constexpr (sizeof(OT) == 4)
          C[(size_t)row * N + col] = acc[i][j][r];
        else
          C[(size_t)row * N + col] = (bf16)acc[i][j][r];
      }
}

// ---------------- RoPE in place (optionally folds softmax scale) ----------------
__global__ void k_rope(bf16* __restrict__ X, const float* __restrict__ cs, const float* __restrict__ sn,
                       int nh, int rowstride, float scale, int total) {
  int idx = blockIdx.x * blockDim.x + threadIdx.x;
  if (idx >= total) return;
  int d = idx & 63;
  int th = idx >> 6;
  int h = th % nh;
  int tok = th / nh;
  size_t base = (size_t)tok * rowstride + h * 128;
  float c = cs[tok * 128 + d], s = sn[tok * 128 + d];
  float x1 = (float)X[base + d];
  float x2 = (float)X[base + d + 64];
  X[base + d] = (bf16)((x1 * c - x2 * s) * scale);
  X[base + d + 64] = (bf16)((x2 * c + x1 * s) * scale);
}

// ---------------- causal flash attention, GQA 4:1, bf16 MFMA ----------------
// grid: (16, NH, B); block = 4 waves. Block p handles q-tiles {p, 31-p} (64 rows each)
// -> exactly 33 KV-tiles (KVBLK=64) per block: perfect causal load balance.
// K staged [64][128] linear + XOR swizzle; Vt staged [128][64] linear + XOR swizzle,
// both via global_load_lds with pre-swizzled per-lane global sources (m201 pattern).
__global__ __launch_bounds__(256) void k_attn(const bf16* __restrict__ Q, const bf16* __restrict__ KV,
                                              const bf16* __restrict__ Vt, bf16* __restrict__ O) {
  constexpr int S = 2048, NH = 16, HD = 128, QSTR = NH * HD, KVSTR = 1024;
  __shared__ __align__(16) bf16 sK[64 * 128];   // [kv][d] linear, swizzled content
  __shared__ __align__(16) bf16 sV[128 * 64];   // [d][kv] linear, swizzled content
  __shared__ __align__(16) bf16 sP[4][16][72];  // per-wave P redistribution (144B rows)
  const int p = blockIdx.x, h = blockIdx.y, b = blockIdx.z;
  const int t = threadIdx.x, w = t >> 6, l = t & 63;
  const int lr = l & 15, lk = l >> 4;
  const int kvh = h >> 2;
  const int swz = (lr & 7) << 4;

  // staging geometry (per-lane global sources, wave-uniform LDS dests)
  const char* kbase = (const char*)(KV + (size_t)b * S * KVSTR + kvh * HD);
  const int krow_l = w * 16 + (l >> 4);        // + c*4
  const int kcol_l = (l & 15) << 4;
  const char* vtbase = (const char*)(Vt + (size_t)(b * 4 + kvh) * HD * S);
  const int vrow_l = w * 32 + (l >> 3);        // + c*8
  const int vcol_l = (l & 7) << 4;
  char* sKb = (char*)sK;
  char* sVb = (char*)sV;

  for (int seg = 0; seg < 2; ++seg) {
    const int qtl = seg ? (31 - p) : p;
    const int qw = qtl * 64 + w * 16;
    const bf16* Qp = Q + (size_t)(b * S + qw + lr) * QSTR + h * HD + lk * 8;
    bf16x8 qf[4];
#pragma unroll
    for (int i = 0; i < 4; ++i) qf[i] = *reinterpret_cast<const bf16x8*>(Qp + i * 32);
    f32x4 oacc[8] = {};
    float mrow[4] = {-3e38f, -3e38f, -3e38f, -3e38f};
    float lsum[4] = {0.f, 0.f, 0.f, 0.f};
    const int ntiles = qtl + 1;
    for (int tt = 0; tt < ntiles; ++tt) {
      const int kvb = tt * 64;
      __syncthreads();  // previous tile's LDS fully consumed
#pragma unroll
      for (int c = 0; c < 4; ++c) {
        const int krow = krow_l + c * 4;
        gload_lds16(kbase + (size_t)(kvb + krow) * 2048 + (kcol_l ^ ((krow & 7) << 4)),
                    sKb + (w * 4 + c) * 1024);
        const int vrow = vrow_l + c * 8;
        gload_lds16(vtbase + (size_t)vrow * (S * 2) + kvb * 2 + (vcol_l ^ ((vrow & 7) << 4)),
                    sVb + (w * 4 + c) * 1024);
      }
      __syncthreads();  // staging complete (compiler drains vmcnt before barrier)
      // ---- QK^T: 16 q-rows x 64 kv per wave ----
      float pm[4][4];
#pragma unroll
      for (int c = 0; c < 4; ++c) {
        f32x4 s4 = {};
#pragma unroll
        for (int kf = 0; kf < 4; ++kf) {
          bf16x8 kf8 = *reinterpret_cast<const bf16x8*>(
              sKb + (c * 16 + lr) * 256 + (((kf * 64) + (lk << 4)) ^ swz));
          s4 = __builtin_amdgcn_mfma_f32_16x16x32_bf16(qf[kf], kf8, s4, 0, 0, 0);
        }
#pragma unroll
        for (int r = 0; r < 4; ++r) pm[c][r] = s4[r];
      }
      // ---- causal mask: only the diagonal tile needs it ----
      if (tt == ntiles - 1) {
#pragma unroll
        for (int c = 0; c < 4; ++c) {
          const int col = kvb + c * 16 + lr;
#pragma unroll
          for (int r = 0; r < 4; ++r)
            if (col > qw + lk * 4 + r) pm[c][r] = -3e38f;
        }
      }
      // ---- online softmax (16-lane group reduce) ----
      float mx[4];
#pragma unroll
      for (int r = 0; r < 4; ++r)
        mx[r] = fmaxf(fmaxf(pm[0][r], pm[1][r]), fmaxf(pm[2][r], pm[3][r]));
#pragma unroll
      for (int off = 1; off < 16; off <<= 1)
#pragma unroll
        for (int r = 0; r < 4; ++r) mx[r] = fmaxf(mx[r], __shfl_xor(mx[r], off));
      float fac[4];
#pragma unroll
      for (int r = 0; r < 4; ++r) {
        float mn = fmaxf(mrow[r], mx[r]);
        fac[r] = __expf(mrow[r] - mn);
        mrow[r] = mn;
      }
#pragma unroll
      for (int c = 0; c < 4; ++c)
#pragma unroll
        for (int r = 0; r < 4; ++r) pm[c][r] = __expf(pm[c][r] - mrow[r]);
      float rs[4];
#pragma unroll
      for (int r = 0; r < 4; ++r)
        rs[r] = (pm[0][r] + pm[1][r]) + (pm[2][r] + pm[3][r]);
#pragma unroll
      for (int off = 1; off < 16; off <<= 1)
#pragma unroll
        for (int r = 0; r < 4; ++r) rs[r] += __shfl_xor(rs[r], off);
#pragma unroll
      for (int r = 0; r < 4; ++r) lsum[r] = lsum[r] * fac[r] + rs[r];
#pragma unroll
      for (int ch = 0; ch < 8; ++ch)
#pragma unroll
        for (int r = 0; r < 4; ++r) oacc[ch][r] *= fac[r];
      // ---- P: D-frag -> A-frag via per-wave LDS ----
#pragma unroll
      for (int c = 0; c < 4; ++c)
#pragma unroll
        for (int r = 0; r < 4; ++r) sP[w][lk * 4 + r][c * 16 + lr] = (bf16)pm[c][r];
      bf16x8 pf0 = *reinterpret_cast<const bf16x8*>(&sP[w][lr][lk * 8]);
      bf16x8 pf1 = *reinterpret_cast<const bf16x8*>(&sP[w][lr][32 + lk * 8]);
      // ---- PV: out[16q][128d] += P[16q][64kv] * V^T ----
#pragma unroll
      for (int ch = 0; ch < 8; ++ch) {
        bf16x8 vf0 = *reinterpret_cast<const bf16x8*>(
            sVb + (ch * 16 + lr) * 128 + ((lk << 4) ^ swz));
        oacc[ch] = __builtin_amdgcn_mfma_f32_16x16x32_bf16(pf0, vf0, oacc[ch], 0, 0, 0);
        bf16x8 vf1 = *reinterpret_cast<const bf16x8*>(
            sVb + (ch * 16 + lr) * 128 + ((64 + (lk << 4)) ^ swz));
        oacc[ch] = __builtin_amdgcn_mfma_f32_16x16x32_bf16(pf1, vf1, oacc[ch], 0, 0, 0);
      }
    }
    float inv[4];
#pragma unroll
    for (int r = 0; r < 4; ++r) inv[r] = 1.0f / lsum[r];
    bf16* Op = O + (size_t)(b * S + qw) * QSTR + h * HD;
#pragma unroll
    for (int ch = 0; ch < 8; ++ch)
#pragma unroll
      for (int r = 0; r < 4; ++r)
        Op[(size_t)(lk * 4 + r) * QSTR + ch * 16 + lr] = (bf16)(oacc[ch][r] * inv[r]);
  }
}

extern "C" void kernel_launch(void* const* d_in, const int* in_sizes, int n_in,
                              void* d_out, int out_size, void* d_ws, size_t ws_size,
                              hipStream_t stream) {
  const float* hs = (const float*)d_in[0];
  // d_in[1] = attention_mask: pure causal, applied analytically
  const float* cosb = (const float*)d_in[2];
  const float* sinb = (const float*)d_in[3];
  const float* Wq = (const float*)d_in[4];
  const float* Wk = (const float*)d_in[5];
  const float* Wv = (const float*)d_in[6];
  const float* Wo = (const float*)d_in[7];
  float* out = (float*)d_out;

  constexpr int B = 2, S = 2048, H = 2048, NH = 16, NKV = 4, HD = 128;
  constexpr int T = B * S;
  constexpr size_t MB = 1024 * 1024;

  // Workspace plan (d_ws 24 MiB; Q/KV/Vt staged inside d_out = 32 MiB):
  //   d_ws[ 0:16M) : Xb (bf16 X), reused as Ob after QKV projections
  //   d_ws[16:24M) : transposed-weight slot: Wqt -> Wkvt -> Wot (serial lifetimes)
  //   d_out[ 0:16M): Qb   d_out[16:24M): KVb   d_out[24:28M): Vt
  //   (all dead before final GEMM overwrites d_out)
  const size_t ws_need = 24 * MB;
  if (ws_size < ws_need) {
    k_diag<<<1, 64, 0, stream>>>(out, 1000.0f + (float)(ws_size / MB));
    return;
  }
  bf16* Xb = (bf16*)d_ws;
  bf16* Wt = (bf16*)((char*)d_ws + 16 * MB);
  bf16* Ob = Xb;
  bf16* Qb = (bf16*)d_out;
  bf16* KVb = (bf16*)((char*)d_out + 16 * MB);
  bf16* Vtb = (bf16*)((char*)d_out + 24 * MB);

  k_cvt_bf16<<<T * H / 4 / 256, 256, 0, stream>>>(hs, Xb, T * H / 4);

  // Q projection
  k_transpose_w<<<dim3(H / 32, NH * HD / 32), 256, 0, stream>>>(Wq, Wt, H, NH * HD);
  k_gemm<bf16><<<dim3(T / 128, NH * HD / 128), 256, 0, stream>>>(Xb, Wt, Qb, T, NH * HD, H);

  // K|V fused projection (N rows 0..511 = K, 512..1023 = V)
  k_transpose_w<<<dim3(H / 32, NKV * HD / 32), 256, 0, stream>>>(Wk, Wt, H, NKV * HD);
  k_transpose_w<<<dim3(H / 32, NKV * HD / 32), 256, 0, stream>>>(Wv, Wt + (size_t)(NKV * HD) * H, H, NKV * HD);
  k_gemm<bf16><<<dim3(T / 128, 1024 / 128), 256, 0, stream>>>(Xb, Wt, KVb, T, 1024, H);

  // V -> Vt[b][kvh][HD][S] (V gets no RoPE)
  k_transpose_v<<<dim3(S / 32, HD / 32, B * NKV), 256, 0, stream>>>(KVb, Vtb);

  // RoPE (fold 1/sqrt(HD) into Q)
  const float qscale = 0.08838834764831845f;
  k_rope<<<(T * NH * 64) / 256, 256, 0, stream>>>(Qb, cosb, sinb, NH, NH * HD, qscale, T * NH * 64);
  k_rope<<<(T * NKV * 64) / 256, 256, 0, stream>>>(KVb, cosb, sinb, NKV, 1024, 1.0f, T * NKV * 64);

  // Attention: reads Q/K/Vt from d_out, writes Ob into d_ws
  k_attn<<<dim3(16, NH, B), 256, 0, stream>>>(Qb, KVb, Vtb, Ob);

  // O projection: reads only d_ws, writes all of d_out
  k_transpose_w<<<dim3(H / 32, H / 32), 256, 0, stream>>>(Wo, Wt, H, H);
  k_gemm<float><<<dim3(T / 128, H / 128), 256, 0, stream>>>(Ob, Wt, out, T, H, H);
}

// Round 4
// 276.247 us; speedup vs baseline: 2.2109x; 1.0483x over previous
//
#include <hip/hip_runtime.h>
#include <hip/hip_bf16.h>

typedef __bf16 bf16;
typedef __bf16 bf16x4 __attribute__((ext_vector_type(4)));
typedef __bf16 bf16x8 __attribute__((ext_vector_type(8)));
typedef float f32x4 __attribute__((ext_vector_type(4)));

__device__ __forceinline__ void gload_lds16(const void* g, void* l) {
  __builtin_amdgcn_global_load_lds((__attribute__((address_space(1))) void*)(g),
                                   (__attribute__((address_space(3))) void*)(l), 16, 0, 0);
}

// ---------------- diagnostic: encode ws_size into output if workspace too small ----
__global__ void k_diag(float* __restrict__ o, float v) { o[threadIdx.x] = v; }

// ---------------- fp32 -> bf16 convert (vectorized) ----------------
__global__ void k_cvt_bf16(const float* __restrict__ x, bf16* __restrict__ y, int n4) {
  int i = blockIdx.x * blockDim.x + threadIdx.x;
  if (i < n4) {
    float4 v = reinterpret_cast<const float4*>(x)[i];
    bf16x4 o = {(bf16)v.x, (bf16)v.y, (bf16)v.z, (bf16)v.w};
    reinterpret_cast<bf16x4*>(y)[i] = o;
  }
}

// ---------------- W (K x N fp32, row-major) -> Wt (N x K bf16) ----------------
__global__ void k_transpose_w(const float* __restrict__ W, bf16* __restrict__ Wt, int K, int N) {
  __shared__ float tile[32][33];
  int kb = blockIdx.x * 32, nb = blockIdx.y * 32;
  int tx = threadIdx.x & 31, ty = threadIdx.x >> 5;
#pragma unroll
  for (int i = 0; i < 32; i += 8)
    tile[ty + i][tx] = W[(size_t)(kb + ty + i) * N + nb + tx];
  __syncthreads();
#pragma unroll
  for (int i = 0; i < 32; i += 8)
    Wt[(size_t)(nb + ty + i) * K + kb + tx] = (bf16)tile[tx][ty + i];
}

// ---------------- V (cols 512..1023 of KVb) -> Vt[b][kvh][HD][S] (bf16) ----------------
__global__ void k_transpose_v(const bf16* __restrict__ KVb, bf16* __restrict__ Vt) {
  __shared__ bf16 tile[32][34];
  constexpr int S = 2048;
  int sb = blockIdx.x * 32, db = blockIdx.y * 32, bh = blockIdx.z;  // bh = b*4+kvh
  int b = bh >> 2, kvh = bh & 3;
  int tx = threadIdx.x & 31, ty = threadIdx.x >> 5;
  const bf16* src = KVb + (size_t)b * S * 1024 + 512 + kvh * 128;
#pragma unroll
  for (int i = 0; i < 32; i += 8)
    tile[ty + i][tx] = src[(size_t)(sb + ty + i) * 1024 + db + tx];
  __syncthreads();
  bf16* dst = Vt + (size_t)bh * 128 * S;
#pragma unroll
  for (int i = 0; i < 32; i += 8)
    dst[(size_t)(db + ty + i) * S + sb + tx] = tile[tx][ty + i];
}

// ---------------- 128x128 bf16 GEMM, double-buffered single-barrier K-loop ----------------
template <typename OT>
__global__ __launch_bounds__(256) void k_gemm(const bf16* __restrict__ A, const bf16* __restrict__ Bt,
                                              OT* __restrict__ C, int M, int N, int Kd) {
  __shared__ __align__(16) bf16 sA[2][128 * 32];
  __shared__ __align__(16) bf16 sB[2][128 * 32];
  const int t = threadIdx.x;
  const int w = t >> 6, l = t & 63;
  const int lr = l & 15, lk = l >> 4;
  const int m0 = blockIdx.x * 128, n0 = blockIdx.y * 128;
  const int wm = (w >> 1) * 64, wn = (w & 1) * 64;
  const bf16* ga = A + (size_t)(m0 + (t >> 2)) * Kd + (t & 3) * 8;
  const bf16* gb = Bt + (size_t)(n0 + (t >> 2)) * Kd + (t & 3) * 8;
  const size_t rowskip = (size_t)64 * Kd;
  auto stage = [&](int k0, int buf) {
    gload_lds16(ga + k0, sA[buf] + w * 512);
    gload_lds16(ga + rowskip + k0, sA[buf] + w * 512 + 2048);
    gload_lds16(gb + k0, sB[buf] + w * 512);
    gload_lds16(gb + rowskip + k0, sB[buf] + w * 512 + 2048);
  };
  f32x4 acc[4][4] = {};
  stage(0, 0);
  __syncthreads();  // vmcnt(0) drain: tile 0 resident
  int cur = 0;
  for (int k0 = 0; k0 < Kd; k0 += 32) {
    if (k0 + 32 < Kd) stage(k0 + 32, cur ^ 1);  // prefetch hides under MFMA below
    bf16x8 af[4], bfr[4];
#pragma unroll
    for (int i = 0; i < 4; ++i)
      af[i] = *reinterpret_cast<const bf16x8*>(sA[cur] + (wm + i * 16 + lr) * 32 + lk * 8);
#pragma unroll
    for (int j = 0; j < 4; ++j)
      bfr[j] = *reinterpret_cast<const bf16x8*>(sB[cur] + (wn + j * 16 + lr) * 32 + lk * 8);
#pragma unroll
    for (int i = 0; i < 4; ++i)
#pragma unroll
      for (int j = 0; j < 4; ++j)
        acc[i][j] = __builtin_amdgcn_mfma_f32_16x16x32_bf16(af[i], bfr[j], acc[i][j], 0, 0, 0);
    __syncthreads();  // drains prefetch (latency already covered) + read-write fence
    cur ^= 1;
  }
#pragma unroll
  for (int i = 0; i < 4; ++i)
#pragma unroll
    for (int j = 0; j < 4; ++j)
#pragma unroll
      for (int r = 0; r < 4; ++r) {
        int row = m0 + wm + i * 16 + lk * 4 + r;
        int col = n0 + wn + j * 16 + lr;
        if constexpr (sizeof(OT) == 4)
          C[(size_t)row * N + col] = acc[i][j][r];
        else
          C[(size_t)row * N + col] = (bf16)acc[i][j][r];
      }
}

// ---------------- RoPE in place (optionally folds softmax scale) ----------------
__global__ void k_rope(bf16* __restrict__ X, const float* __restrict__ cs, const float* __restrict__ sn,
                       int nh, int rowstride, float scale, int total) {
  int idx = blockIdx.x * blockDim.x + threadIdx.x;
  if (idx >= total) return;
  int d = idx & 63;
  int th = idx >> 6;
  int h = th % nh;
  int tok = th / nh;
  size_t base = (size_t)tok * rowstride + h * 128;
  float c = cs[tok * 128 + d], s = sn[tok * 128 + d];
  float x1 = (float)X[base + d];
  float x2 = (float)X[base + d + 64];
  X[base + d] = (bf16)((x1 * c - x2 * s) * scale);
  X[base + d + 64] = (bf16)((x2 * c + x1 * s) * scale);
}

// ---------------- causal flash attention, GQA 4:1, bf16 MFMA ----------------
// grid: (16, NH, B); block = 4 waves. Block p handles q-tiles {p, 31-p}: 33 KV-tiles, uniform.
// K/V double-buffered in LDS, staged via global_load_lds with pre-swizzled global sources;
// ONE __syncthreads per tile: prefetch(t+1) issued before compute(t), drain at loop end.
__global__ __launch_bounds__(256) void k_attn(const bf16* __restrict__ Q, const bf16* __restrict__ KV,
                                              const bf16* __restrict__ Vt, bf16* __restrict__ O) {
  constexpr int S = 2048, NH = 16, HD = 128, QSTR = NH * HD, KVSTR = 1024;
  __shared__ __align__(16) bf16 sK[2][64 * 128];   // [kv][d] linear, swizzled content
  __shared__ __align__(16) bf16 sV[2][128 * 64];   // [d][kv] linear, swizzled content
  __shared__ __align__(16) bf16 sP[4][16][72];     // per-wave P redistribution
  const int p = blockIdx.x, h = blockIdx.y, b = blockIdx.z;
  const int t = threadIdx.x, w = t >> 6, l = t & 63;
  const int lr = l & 15, lk = l >> 4;
  const int kvh = h >> 2;
  const int swz = (lr & 7) << 4;

  const char* kbase = (const char*)(KV + (size_t)b * S * KVSTR + kvh * HD);
  const int krow_l = w * 16 + (l >> 4);
  const int kcol_l = (l & 15) << 4;
  const char* vtbase = (const char*)(Vt + (size_t)(b * 4 + kvh) * HD * S);
  const int vrow_l = w * 32 + (l >> 3);
  const int vcol_l = (l & 7) << 4;
  char* sKb = (char*)sK;
  char* sVb = (char*)sV;
  auto stage = [&](int kvb, int buf) {
#pragma unroll
    for (int c = 0; c < 4; ++c) {
      const int krow = krow_l + c * 4;
      gload_lds16(kbase + (size_t)(kvb + krow) * 2048 + (kcol_l ^ ((krow & 7) << 4)),
                  sKb + buf * 16384 + (w * 4 + c) * 1024);
      const int vrow = vrow_l + c * 8;
      gload_lds16(vtbase + (size_t)vrow * (S * 2) + kvb * 2 + (vcol_l ^ ((vrow & 7) << 4)),
                  sVb + buf * 16384 + (w * 4 + c) * 1024);
    }
  };

  for (int seg = 0; seg < 2; ++seg) {
    const int qtl = seg ? (31 - p) : p;
    const int qw = qtl * 64 + w * 16;
    const int ntiles = qtl + 1;
    int cur = 0;
    stage(0, 0);
    const bf16* Qp = Q + (size_t)(b * S + qw + lr) * QSTR + h * HD + lk * 8;
    bf16x8 qf[4];
#pragma unroll
    for (int i = 0; i < 4; ++i) qf[i] = *reinterpret_cast<const bf16x8*>(Qp + i * 32);
    f32x4 oacc[8] = {};
    float mrow[4] = {-3e38f, -3e38f, -3e38f, -3e38f};
    float lsum[4] = {0.f, 0.f, 0.f, 0.f};
    __syncthreads();  // tile 0 resident
    for (int tt = 0; tt < ntiles; ++tt) {
      const int kvb = tt * 64;
      if (tt + 1 < ntiles) stage(kvb + 64, cur ^ 1);  // prefetch next tile
      const char* sKc = sKb + cur * 16384;
      const char* sVc = sVb + cur * 16384;
      // ---- QK^T: 16 q-rows x 64 kv per wave ----
      float pm[4][4];
#pragma unroll
      for (int c = 0; c < 4; ++c) {
        f32x4 s4 = {};
#pragma unroll
        for (int kf = 0; kf < 4; ++kf) {
          bf16x8 kf8 = *reinterpret_cast<const bf16x8*>(
              sKc + (c * 16 + lr) * 256 + (((kf * 64) + (lk << 4)) ^ swz));
          s4 = __builtin_amdgcn_mfma_f32_16x16x32_bf16(qf[kf], kf8, s4, 0, 0, 0);
        }
#pragma unroll
        for (int r = 0; r < 4; ++r) pm[c][r] = s4[r];
      }
      // ---- causal mask: diagonal tile only ----
      if (tt == ntiles - 1) {
#pragma unroll
        for (int c = 0; c < 4; ++c) {
          const int col = kvb + c * 16 + lr;
#pragma unroll
          for (int r = 0; r < 4; ++r)
            if (col > qw + lk * 4 + r) pm[c][r] = -3e38f;
        }
      }
      // ---- online softmax (16-lane group reduce) ----
      float mx[4];
#pragma unroll
      for (int r = 0; r < 4; ++r)
        mx[r] = fmaxf(fmaxf(pm[0][r], pm[1][r]), fmaxf(pm[2][r], pm[3][r]));
#pragma unroll
      for (int off = 1; off < 16; off <<= 1)
#pragma unroll
        for (int r = 0; r < 4; ++r) mx[r] = fmaxf(mx[r], __shfl_xor(mx[r], off));
      float fac[4];
#pragma unroll
      for (int r = 0; r < 4; ++r) {
        float mn = fmaxf(mrow[r], mx[r]);
        fac[r] = __expf(mrow[r] - mn);
        mrow[r] = mn;
      }
#pragma unroll
      for (int c = 0; c < 4; ++c)
#pragma unroll
        for (int r = 0; r < 4; ++r) pm[c][r] = __expf(pm[c][r] - mrow[r]);
      float rs[4];
#pragma unroll
      for (int r = 0; r < 4; ++r)
        rs[r] = (pm[0][r] + pm[1][r]) + (pm[2][r] + pm[3][r]);
#pragma unroll
      for (int off = 1; off < 16; off <<= 1)
#pragma unroll
        for (int r = 0; r < 4; ++r) rs[r] += __shfl_xor(rs[r], off);
#pragma unroll
      for (int r = 0; r < 4; ++r) lsum[r] = lsum[r] * fac[r] + rs[r];
#pragma unroll
      for (int ch = 0; ch < 8; ++ch)
#pragma unroll
        for (int r = 0; r < 4; ++r) oacc[ch][r] *= fac[r];
      // ---- P: D-frag -> A-frag via per-wave LDS ----
#pragma unroll
      for (int c = 0; c < 4; ++c)
#pragma unroll
        for (int r = 0; r < 4; ++r) sP[w][lk * 4 + r][c * 16 + lr] = (bf16)pm[c][r];
      bf16x8 pf0 = *reinterpret_cast<const bf16x8*>(&sP[w][lr][lk * 8]);
      bf16x8 pf1 = *reinterpret_cast<const bf16x8*>(&sP[w][lr][32 + lk * 8]);
      // ---- PV: out[16q][128d] += P[16q][64kv] * V^T ----
#pragma unroll
      for (int ch = 0; ch < 8; ++ch) {
        bf16x8 vf0 = *reinterpret_cast<const bf16x8*>(
            sVc + (ch * 16 + lr) * 128 + ((lk << 4) ^ swz));
        oacc[ch] = __builtin_amdgcn_mfma_f32_16x16x32_bf16(pf0, vf0, oacc[ch], 0, 0, 0);
        bf16x8 vf1 = *reinterpret_cast<const bf16x8*>(
            sVc + (ch * 16 + lr) * 128 + ((64 + (lk << 4)) ^ swz));
        oacc[ch] = __builtin_amdgcn_mfma_f32_16x16x32_bf16(pf1, vf1, oacc[ch], 0, 0, 0);
      }
      __syncthreads();  // single barrier per tile: drains prefetch, fences reuse
      cur ^= 1;
    }
    float inv[4];
#pragma unroll
    for (int r = 0; r < 4; ++r) inv[r] = 1.0f / lsum[r];
    bf16* Op = O + (size_t)(b * S + qw) * QSTR + h * HD;
#pragma unroll
    for (int ch = 0; ch < 8; ++ch)
#pragma unroll
      for (int r = 0; r < 4; ++r)
        Op[(size_t)(lk * 4 + r) * QSTR + ch * 16 + lr] = (bf16)(oacc[ch][r] * inv[r]);
  }
}

extern "C" void kernel_launch(void* const* d_in, const int* in_sizes, int n_in,
                              void* d_out, int out_size, void* d_ws, size_t ws_size,
                              hipStream_t stream) {
  const float* hs = (const float*)d_in[0];
  // d_in[1] = attention_mask: pure causal, applied analytically
  const float* cosb = (const float*)d_in[2];
  const float* sinb = (const float*)d_in[3];
  const float* Wq = (const float*)d_in[4];
  const float* Wk = (const float*)d_in[5];
  const float* Wv = (const float*)d_in[6];
  const float* Wo = (const float*)d_in[7];
  float* out = (float*)d_out;

  constexpr int B = 2, S = 2048, H = 2048, NH = 16, NKV = 4, HD = 128;
  constexpr int T = B * S;
  constexpr size_t MB = 1024 * 1024;

  // Workspace plan (d_ws 24 MiB; Q/KV/Vt staged inside d_out = 32 MiB):
  //   d_ws[ 0:16M) : Xb (bf16 X), reused as Ob after QKV projections
  //   d_ws[16:24M) : transposed-weight slot: Wqt -> Wkvt -> Wot (serial lifetimes)
  //   d_out[ 0:16M): Qb   d_out[16:24M): KVb   d_out[24:28M): Vt
  const size_t ws_need = 24 * MB;
  if (ws_size < ws_need) {
    k_diag<<<1, 64, 0, stream>>>(out, 1000.0f + (float)(ws_size / MB));
    return;
  }
  bf16* Xb = (bf16*)d_ws;
  bf16* Wt = (bf16*)((char*)d_ws + 16 * MB);
  bf16* Ob = Xb;
  bf16* Qb = (bf16*)d_out;
  bf16* KVb = (bf16*)((char*)d_out + 16 * MB);
  bf16* Vtb = (bf16*)((char*)d_out + 24 * MB);

  k_cvt_bf16<<<T * H / 4 / 256, 256, 0, stream>>>(hs, Xb, T * H / 4);

  // Q projection
  k_transpose_w<<<dim3(H / 32, NH * HD / 32), 256, 0, stream>>>(Wq, Wt, H, NH * HD);
  k_gemm<bf16><<<dim3(T / 128, NH * HD / 128), 256, 0, stream>>>(Xb, Wt, Qb, T, NH * HD, H);

  // K|V fused projection (N rows 0..511 = K, 512..1023 = V)
  k_transpose_w<<<dim3(H / 32, NKV * HD / 32), 256, 0, stream>>>(Wk, Wt, H, NKV * HD);
  k_transpose_w<<<dim3(H / 32, NKV * HD / 32), 256, 0, stream>>>(Wv, Wt + (size_t)(NKV * HD) * H, H, NKV * HD);
  k_gemm<bf16><<<dim3(T / 128, 1024 / 128), 256, 0, stream>>>(Xb, Wt, KVb, T, 1024, H);

  // V -> Vt[b][kvh][HD][S] (V gets no RoPE)
  k_transpose_v<<<dim3(S / 32, HD / 32, B * NKV), 256, 0, stream>>>(KVb, Vtb);

  // RoPE (fold 1/sqrt(HD) into Q)
  const float qscale = 0.08838834764831845f;
  k_rope<<<(T * NH * 64) / 256, 256, 0, stream>>>(Qb, cosb, sinb, NH, NH * HD, qscale, T * NH * 64);
  k_rope<<<(T * NKV * 64) / 256, 256, 0, stream>>>(KVb, cosb, sinb, NKV, 1024, 1.0f, T * NKV * 64);

  // Attention: reads Q/K/Vt from d_out, writes Ob into d_ws
  k_attn<<<dim3(16, NH, B), 256, 0, stream>>>(Qb, KVb, Vtb, Ob);

  // O projection: reads only d_ws, writes all of d_out
  k_transpose_w<<<dim3(H / 32, H / 32), 256, 0, stream>>>(Wo, Wt, H, H);
  k_gemm<float><<<dim3(T / 128, H / 128), 256, 0, stream>>>(Ob, Wt, out, T, H, H);
}

// Round 5
// 255.904 us; speedup vs baseline: 2.3867x; 1.0795x over previous
//
#include <hip/hip_runtime.h>
#include <hip/hip_bf16.h>

typedef __bf16 bf16;
typedef __bf16 bf16x4 __attribute__((ext_vector_type(4)));
typedef __bf16 bf16x8 __attribute__((ext_vector_type(8)));
typedef float f32x4 __attribute__((ext_vector_type(4)));

__device__ __forceinline__ void gload_lds16(const void* g, void* l) {
  __builtin_amdgcn_global_load_lds((__attribute__((address_space(1))) void*)(g),
                                   (__attribute__((address_space(3))) void*)(l), 16, 0, 0);
}
// raw 2^x (v_exp_f32 IS exp2); avoids libm wrapper + the ln->log2 multiply
__device__ __forceinline__ float fexp2(float x) {
  float r;
  asm volatile("v_exp_f32 %0, %1" : "=v"(r) : "v"(x));
  return r;
}

// ---------------- diagnostic: encode ws_size into output if workspace too small ----
__global__ void k_diag(float* __restrict__ o, float v) { o[threadIdx.x] = v; }

// ---------------- fp32 -> bf16 convert (vectorized) ----------------
__global__ void k_cvt_bf16(const float* __restrict__ x, bf16* __restrict__ y, int n4) {
  int i = blockIdx.x * blockDim.x + threadIdx.x;
  if (i < n4) {
    float4 v = reinterpret_cast<const float4*>(x)[i];
    bf16x4 o = {(bf16)v.x, (bf16)v.y, (bf16)v.z, (bf16)v.w};
    reinterpret_cast<bf16x4*>(y)[i] = o;
  }
}

// ---------------- W (K x N fp32, row-major) -> Wt (N x K bf16) ----------------
__global__ void k_transpose_w(const float* __restrict__ W, bf16* __restrict__ Wt, int K, int N) {
  __shared__ float tile[32][33];
  int kb = blockIdx.x * 32, nb = blockIdx.y * 32;
  int tx = threadIdx.x & 31, ty = threadIdx.x >> 5;
#pragma unroll
  for (int i = 0; i < 32; i += 8)
    tile[ty + i][tx] = W[(size_t)(kb + ty + i) * N + nb + tx];
  __syncthreads();
#pragma unroll
  for (int i = 0; i < 32; i += 8)
    Wt[(size_t)(nb + ty + i) * K + kb + tx] = (bf16)tile[tx][ty + i];
}

// ---------------- V (cols 512..1023 of KVb) -> Vt[b][kvh][HD][S] (bf16) ----------------
__global__ void k_transpose_v(const bf16* __restrict__ KVb, bf16* __restrict__ Vt) {
  __shared__ bf16 tile[32][34];
  constexpr int S = 2048;
  int sb = blockIdx.x * 32, db = blockIdx.y * 32, bh = blockIdx.z;  // bh = b*4+kvh
  int b = bh >> 2, kvh = bh & 3;
  int tx = threadIdx.x & 31, ty = threadIdx.x >> 5;
  const bf16* src = KVb + (size_t)b * S * 1024 + 512 + kvh * 128;
#pragma unroll
  for (int i = 0; i < 32; i += 8)
    tile[ty + i][tx] = src[(size_t)(sb + ty + i) * 1024 + db + tx];
  __syncthreads();
  bf16* dst = Vt + (size_t)bh * 128 * S;
#pragma unroll
  for (int i = 0; i < 32; i += 8)
    dst[(size_t)(db + ty + i) * S + sb + tx] = tile[tx][ty + i];
}

// ---------------- 128x128 bf16 GEMM, double-buffered, XCD-swizzled ----------------
template <typename OT>
__global__ __launch_bounds__(256) void k_gemm(const bf16* __restrict__ A, const bf16* __restrict__ Bt,
                                              OT* __restrict__ C, int M, int N, int Kd) {
  __shared__ __align__(16) bf16 sA[2][128 * 32];
  __shared__ __align__(16) bf16 sB[2][128 * 32];
  const int t = threadIdx.x;
  const int w = t >> 6, l = t & 63;
  const int lr = l & 15, lk = l >> 4;
  // XCD-aware swizzle (grid % 8 == 0 guaranteed by launch shapes):
  // consecutive swizzled ids share an N-panel -> B stays L2-resident per XCD.
  const int gx = gridDim.x, nwg = gx * gridDim.y;
  const int flat = blockIdx.y * gx + blockIdx.x;
  const int vid = (flat & 7) * (nwg >> 3) + (flat >> 3);
  const int m0 = (vid % gx) * 128, n0 = (vid / gx) * 128;
  const int wm = (w >> 1) * 64, wn = (w & 1) * 64;
  const bf16* ga = A + (size_t)(m0 + (t >> 2)) * Kd + (t & 3) * 8;
  const bf16* gb = Bt + (size_t)(n0 + (t >> 2)) * Kd + (t & 3) * 8;
  const size_t rowskip = (size_t)64 * Kd;
  auto stage = [&](int k0, int buf) {
    gload_lds16(ga + k0, sA[buf] + w * 512);
    gload_lds16(ga + rowskip + k0, sA[buf] + w * 512 + 2048);
    gload_lds16(gb + k0, sB[buf] + w * 512);
    gload_lds16(gb + rowskip + k0, sB[buf] + w * 512 + 2048);
  };
  f32x4 acc[4][4] = {};
  stage(0, 0);
  __syncthreads();
  int cur = 0;
  for (int k0 = 0; k0 < Kd; k0 += 32) {
    if (k0 + 32 < Kd) stage(k0 + 32, cur ^ 1);
    bf16x8 af[4], bfr[4];
#pragma unroll
    for (int i = 0; i < 4; ++i)
      af[i] = *reinterpret_cast<const bf16x8*>(sA[cur] + (wm + i * 16 + lr) * 32 + lk * 8);
#pragma unroll
    for (int j = 0; j < 4; ++j)
      bfr[j] = *reinterpret_cast<const bf16x8*>(sB[cur] + (wn + j * 16 + lr) * 32 + lk * 8);
#pragma unroll
    for (int i = 0; i < 4; ++i)
#pragma unroll
      for (int j = 0; j < 4; ++j)
        acc[i][j] = __builtin_amdgcn_mfma_f32_16x16x32_bf16(af[i], bfr[j], acc[i][j], 0, 0, 0);
    __syncthreads();
    cur ^= 1;
  }
#pragma unroll
  for (int i = 0; i < 4; ++i)
#pragma unroll
    for (int j = 0; j < 4; ++j)
#pragma unroll
      for (int r = 0; r < 4; ++r) {
        int row = m0 + wm + i * 16 + lk * 4 + r;
        int col = n0 + wn + j * 16 + lr;
        if constexpr (sizeof(OT) == 4)
          C[(size_t)row * N + col] = acc[i][j][r];
        else
          C[(size_t)row * N + col] = (bf16)acc[i][j][r];
      }
}

// ---------------- RoPE in place (optionally folds score scale into Q) ----------------
__global__ void k_rope(bf16* __restrict__ X, const float* __restrict__ cs, const float* __restrict__ sn,
                       int nh, int rowstride, float scale, int total) {
  int idx = blockIdx.x * blockDim.x + threadIdx.x;
  if (idx >= total) return;
  int d = idx & 63;
  int th = idx >> 6;
  int h = th % nh;
  int tok = th / nh;
  size_t base = (size_t)tok * rowstride + h * 128;
  float c = cs[tok * 128 + d], s = sn[tok * 128 + d];
  float x1 = (float)X[base + d];
  float x2 = (float)X[base + d + 64];
  X[base + d] = (bf16)((x1 * c - x2 * s) * scale);
  X[base + d + 64] = (bf16)((x2 * c + x1 * s) * scale);
}

// ---------------- causal flash attention, GQA 4:1, bf16 MFMA ----------------
// 1D grid 512, swizzled so each XCD owns one (b,kvh): KV (1MB) + Q slice L2-resident.
// Block p handles q-tiles {p, 31-p}: 33 KV-tiles (KVBLK=64), uniform causal load.
// Scores in log2 domain (log2e folded into Q); defer-max softmax (THR=8);
// per-lane partial lsum reduced once at the end.
__global__ __launch_bounds__(256) void k_attn(const bf16* __restrict__ Q, const bf16* __restrict__ KV,
                                              const bf16* __restrict__ Vt, bf16* __restrict__ O) {
  constexpr int S = 2048, NH = 16, HD = 128, QSTR = NH * HD, KVSTR = 1024;
  __shared__ __align__(16) bf16 sK[2][64 * 128];
  __shared__ __align__(16) bf16 sV[2][128 * 64];
  __shared__ __align__(16) bf16 sP[4][16][72];
  const int bid = blockIdx.x;
  const int vid = (bid & 7) * 64 + (bid >> 3);  // XCD swizzle: 64 consecutive per XCD
  const int p = vid & 15, bh = vid >> 4;
  const int h = bh & 15, b = bh >> 4;
  const int t = threadIdx.x, w = t >> 6, l = t & 63;
  const int lr = l & 15, lk = l >> 4;
  const int kvh = h >> 2;
  const int swz = (lr & 7) << 4;

  const char* kbase = (const char*)(KV + (size_t)b * S * KVSTR + kvh * HD);
  const int krow_l = w * 16 + (l >> 4);
  const int kcol_l = (l & 15) << 4;
  const char* vtbase = (const char*)(Vt + (size_t)(b * 4 + kvh) * HD * S);
  const int vrow_l = w * 32 + (l >> 3);
  const int vcol_l = (l & 7) << 4;
  char* sKb = (char*)sK;
  char* sVb = (char*)sV;
  auto stage = [&](int kvb, int buf) {
#pragma unroll
    for (int c = 0; c < 4; ++c) {
      const int krow = krow_l + c * 4;
      gload_lds16(kbase + (size_t)(kvb + krow) * 2048 + (kcol_l ^ ((krow & 7) << 4)),
                  sKb + buf * 16384 + (w * 4 + c) * 1024);
      const int vrow = vrow_l + c * 8;
      gload_lds16(vtbase + (size_t)vrow * (S * 2) + kvb * 2 + (vcol_l ^ ((vrow & 7) << 4)),
                  sVb + buf * 16384 + (w * 4 + c) * 1024);
    }
  };

  for (int seg = 0; seg < 2; ++seg) {
    const int qtl = seg ? (31 - p) : p;
    const int qw = qtl * 64 + w * 16;
    const int ntiles = qtl + 1;
    int cur = 0;
    stage(0, 0);
    const bf16* Qp = Q + (size_t)(b * S + qw + lr) * QSTR + h * HD + lk * 8;
    bf16x8 qf[4];
#pragma unroll
    for (int i = 0; i < 4; ++i) qf[i] = *reinterpret_cast<const bf16x8*>(Qp + i * 32);
    f32x4 oacc[8] = {};
    float mrow[4] = {-3e38f, -3e38f, -3e38f, -3e38f};
    float lsum[4] = {0.f, 0.f, 0.f, 0.f};  // per-lane partial (cols this lane owns)
    __syncthreads();
    for (int tt = 0; tt < ntiles; ++tt) {
      const int kvb = tt * 64;
      if (tt + 1 < ntiles) stage(kvb + 64, cur ^ 1);
      const char* sKc = sKb + cur * 16384;
      const char* sVc = sVb + cur * 16384;
      // ---- QK^T (scores in log2 domain) ----
      float pm[4][4];
#pragma unroll
      for (int c = 0; c < 4; ++c) {
        f32x4 s4 = {};
#pragma unroll
        for (int kf = 0; kf < 4; ++kf) {
          bf16x8 kf8 = *reinterpret_cast<const bf16x8*>(
              sKc + (c * 16 + lr) * 256 + (((kf * 64) + (lk << 4)) ^ swz));
          s4 = __builtin_amdgcn_mfma_f32_16x16x32_bf16(qf[kf], kf8, s4, 0, 0, 0);
        }
#pragma unroll
        for (int r = 0; r < 4; ++r) pm[c][r] = s4[r];
      }
      // ---- causal mask: diagonal tile only ----
      if (tt == ntiles - 1) {
#pragma unroll
        for (int c = 0; c < 4; ++c) {
          const int col = kvb + c * 16 + lr;
#pragma unroll
          for (int r = 0; r < 4; ++r)
            if (col > qw + lk * 4 + r) pm[c][r] = -3e38f;
        }
      }
      // ---- defer-max online softmax ----
      float pmax[4];
#pragma unroll
      for (int r = 0; r < 4; ++r)
        pmax[r] = fmaxf(fmaxf(pm[0][r], pm[1][r]), fmaxf(pm[2][r], pm[3][r]));
      bool hi = (pmax[0] > mrow[0] + 8.f) | (pmax[1] > mrow[1] + 8.f) |
                (pmax[2] > mrow[2] + 8.f) | (pmax[3] > mrow[3] + 8.f);
      if (__any(hi)) {  // rare after tile 0: full rescale path
        float mx[4];
#pragma unroll
        for (int r = 0; r < 4; ++r) mx[r] = pmax[r];
#pragma unroll
        for (int off = 1; off < 16; off <<= 1)
#pragma unroll
          for (int r = 0; r < 4; ++r) mx[r] = fmaxf(mx[r], __shfl_xor(mx[r], off));
#pragma unroll
        for (int r = 0; r < 4; ++r) {
          float mn = fmaxf(mrow[r], mx[r]);
          float fac = fexp2(mrow[r] - mn);
          mrow[r] = mn;
          lsum[r] *= fac;
#pragma unroll
          for (int ch = 0; ch < 8; ++ch) oacc[ch][r] *= fac;
        }
      }
#pragma unroll
      for (int c = 0; c < 4; ++c)
#pragma unroll
        for (int r = 0; r < 4; ++r) pm[c][r] = fexp2(pm[c][r] - mrow[r]);  // <= 2^8
#pragma unroll
      for (int r = 0; r < 4; ++r)
        lsum[r] += (pm[0][r] + pm[1][r]) + (pm[2][r] + pm[3][r]);
      // ---- P: D-frag -> A-frag via per-wave LDS ----
#pragma unroll
      for (int c = 0; c < 4; ++c)
#pragma unroll
        for (int r = 0; r < 4; ++r) sP[w][lk * 4 + r][c * 16 + lr] = (bf16)pm[c][r];
      bf16x8 pf0 = *reinterpret_cast<const bf16x8*>(&sP[w][lr][lk * 8]);
      bf16x8 pf1 = *reinterpret_cast<const bf16x8*>(&sP[w][lr][32 + lk * 8]);
      // ---- PV ----
#pragma unroll
      for (int ch = 0; ch < 8; ++ch) {
        bf16x8 vf0 = *reinterpret_cast<const bf16x8*>(
            sVc + (ch * 16 + lr) * 128 + ((lk << 4) ^ swz));
        oacc[ch] = __builtin_amdgcn_mfma_f32_16x16x32_bf16(pf0, vf0, oacc[ch], 0, 0, 0);
        bf16x8 vf1 = *reinterpret_cast<const bf16x8*>(
            sVc + (ch * 16 + lr) * 128 + ((64 + (lk << 4)) ^ swz));
        oacc[ch] = __builtin_amdgcn_mfma_f32_16x16x32_bf16(pf1, vf1, oacc[ch], 0, 0, 0);
      }
      __syncthreads();
      cur ^= 1;
    }
    // final cross-lane sum reduce (16-lane groups), then normalize+write
#pragma unroll
    for (int off = 1; off < 16; off <<= 1)
#pragma unroll
      for (int r = 0; r < 4; ++r) lsum[r] += __shfl_xor(lsum[r], off);
    float inv[4];
#pragma unroll
    for (int r = 0; r < 4; ++r) inv[r] = 1.0f / lsum[r];
    bf16* Op = O + (size_t)(b * S + qw) * QSTR + h * HD;
#pragma unroll
    for (int ch = 0; ch < 8; ++ch)
#pragma unroll
      for (int r = 0; r < 4; ++r)
        Op[(size_t)(lk * 4 + r) * QSTR + ch * 16 + lr] = (bf16)(oacc[ch][r] * inv[r]);
  }
}

extern "C" void kernel_launch(void* const* d_in, const int* in_sizes, int n_in,
                              void* d_out, int out_size, void* d_ws, size_t ws_size,
                              hipStream_t stream) {
  const float* hs = (const float*)d_in[0];
  // d_in[1] = attention_mask: pure causal, applied analytically
  const float* cosb = (const float*)d_in[2];
  const float* sinb = (const float*)d_in[3];
  const float* Wq = (const float*)d_in[4];
  const float* Wk = (const float*)d_in[5];
  const float* Wv = (const float*)d_in[6];
  const float* Wo = (const float*)d_in[7];
  float* out = (float*)d_out;

  constexpr int B = 2, S = 2048, H = 2048, NH = 16, NKV = 4, HD = 128;
  constexpr int T = B * S;
  constexpr size_t MB = 1024 * 1024;

  // Workspace plan (d_ws 24 MiB; Q/KV/Vt staged inside d_out = 32 MiB):
  //   d_ws[ 0:16M) : Xb (bf16 X), reused as Ob after QKV projections
  //   d_ws[16:24M) : transposed-weight slot: Wqt -> Wkvt -> Wot (serial lifetimes)
  //   d_out[ 0:16M): Qb   d_out[16:24M): KVb   d_out[24:28M): Vt
  const size_t ws_need = 24 * MB;
  if (ws_size < ws_need) {
    k_diag<<<1, 64, 0, stream>>>(out, 1000.0f + (float)(ws_size / MB));
    return;
  }
  bf16* Xb = (bf16*)d_ws;
  bf16* Wt = (bf16*)((char*)d_ws + 16 * MB);
  bf16* Ob = Xb;
  bf16* Qb = (bf16*)d_out;
  bf16* KVb = (bf16*)((char*)d_out + 16 * MB);
  bf16* Vtb = (bf16*)((char*)d_out + 24 * MB);

  k_cvt_bf16<<<T * H / 4 / 256, 256, 0, stream>>>(hs, Xb, T * H / 4);

  // Q projection
  k_transpose_w<<<dim3(H / 32, NH * HD / 32), 256, 0, stream>>>(Wq, Wt, H, NH * HD);
  k_gemm<bf16><<<dim3(T / 128, NH * HD / 128), 256, 0, stream>>>(Xb, Wt, Qb, T, NH * HD, H);

  // K|V fused projection (N rows 0..511 = K, 512..1023 = V)
  k_transpose_w<<<dim3(H / 32, NKV * HD / 32), 256, 0, stream>>>(Wk, Wt, H, NKV * HD);
  k_transpose_w<<<dim3(H / 32, NKV * HD / 32), 256, 0, stream>>>(Wv, Wt + (size_t)(NKV * HD) * H, H, NKV * HD);
  k_gemm<bf16><<<dim3(T / 128, 1024 / 128), 256, 0, stream>>>(Xb, Wt, KVb, T, 1024, H);

  // V -> Vt[b][kvh][HD][S] (V gets no RoPE)
  k_transpose_v<<<dim3(S / 32, HD / 32, B * NKV), 256, 0, stream>>>(KVb, Vtb);

  // RoPE; Q additionally folds log2(e)/sqrt(HD) so QK^T lands in log2 domain
  const float qscale = 0.12751743f;  // log2(e) / sqrt(128)
  k_rope<<<(T * NH * 64) / 256, 256, 0, stream>>>(Qb, cosb, sinb, NH, NH * HD, qscale, T * NH * 64);
  k_rope<<<(T * NKV * 64) / 256, 256, 0, stream>>>(KVb, cosb, sinb, NKV, 1024, 1.0f, T * NKV * 64);

  // Attention: reads Q/K/Vt from d_out, writes Ob into d_ws
  k_attn<<<512, 256, 0, stream>>>(Qb, KVb, Vtb, Ob);

  // O projection: reads only d_ws, writes all of d_out
  k_transpose_w<<<dim3(H / 32, H / 32), 256, 0, stream>>>(Wo, Wt, H, H);
  k_gemm<float><<<dim3(T / 128, H / 128), 256, 0, stream>>>(Ob, Wt, out, T, H, H);
}

// Round 6
// 226.015 us; speedup vs baseline: 2.7023x; 1.1322x over previous
//
#include <hip/hip_runtime.h>
#include <hip/hip_bf16.h>

typedef __bf16 bf16;
typedef __bf16 bf16x4 __attribute__((ext_vector_type(4)));
typedef __bf16 bf16x8 __attribute__((ext_vector_type(8)));
typedef float f32x4 __attribute__((ext_vector_type(4)));

__device__ __forceinline__ void gload_lds16(const void* g, void* l) {
  __builtin_amdgcn_global_load_lds((__attribute__((address_space(1))) void*)(g),
                                   (__attribute__((address_space(3))) void*)(l), 16, 0, 0);
}
// raw 2^x (v_exp_f32 IS exp2)
__device__ __forceinline__ float fexp2(float x) {
  float r;
  asm volatile("v_exp_f32 %0, %1" : "=v"(r) : "v"(x));
  return r;
}
#define S_WAITCNT_VM(n) asm volatile("s_waitcnt vmcnt(" #n ")" ::: "memory")

// ---------------- diagnostic: encode ws_size into output if workspace too small ----
__global__ void k_diag(float* __restrict__ o, float v) { o[threadIdx.x] = v; }

// ---------------- fp32 -> bf16 convert (vectorized) ----------------
__global__ void k_cvt_bf16(const float* __restrict__ x, bf16* __restrict__ y, int n4) {
  int i = blockIdx.x * blockDim.x + threadIdx.x;
  if (i < n4) {
    float4 v = reinterpret_cast<const float4*>(x)[i];
    bf16x4 o = {(bf16)v.x, (bf16)v.y, (bf16)v.z, (bf16)v.w};
    reinterpret_cast<bf16x4*>(y)[i] = o;
  }
}

// ---------------- W (K x N fp32, row-major) -> Wt (N x K bf16) ----------------
__global__ void k_transpose_w(const float* __restrict__ W, bf16* __restrict__ Wt, int K, int N) {
  __shared__ float tile[32][33];
  int kb = blockIdx.x * 32, nb = blockIdx.y * 32;
  int tx = threadIdx.x & 31, ty = threadIdx.x >> 5;
#pragma unroll
  for (int i = 0; i < 32; i += 8)
    tile[ty + i][tx] = W[(size_t)(kb + ty + i) * N + nb + tx];
  __syncthreads();
#pragma unroll
  for (int i = 0; i < 32; i += 8)
    Wt[(size_t)(nb + ty + i) * K + kb + tx] = (bf16)tile[tx][ty + i];
}

// ---------------- V (cols 512..1023 of KVb) -> Vt[b][kvh][HD][S] (bf16) ----------------
__global__ void k_transpose_v(const bf16* __restrict__ KVb, bf16* __restrict__ Vt) {
  __shared__ bf16 tile[32][34];
  constexpr int S = 2048;
  int sb = blockIdx.x * 32, db = blockIdx.y * 32, bh = blockIdx.z;  // bh = b*4+kvh
  int b = bh >> 2, kvh = bh & 3;
  int tx = threadIdx.x & 31, ty = threadIdx.x >> 5;
  const bf16* src = KVb + (size_t)b * S * 1024 + 512 + kvh * 128;
#pragma unroll
  for (int i = 0; i < 32; i += 8)
    tile[ty + i][tx] = src[(size_t)(sb + ty + i) * 1024 + db + tx];
  __syncthreads();
  bf16* dst = Vt + (size_t)bh * 128 * S;
#pragma unroll
  for (int i = 0; i < 32; i += 8)
    dst[(size_t)(db + ty + i) * S + sb + tx] = tile[tx][ty + i];
}

// ---------------- BMx128 bf16 GEMM: counted-vmcnt dbuf, st_16x32 swizzle, 8 waves ----
// C[M,N] = A[M,K] * Bt[N,K]^T.  LDS: [16][32]-bf16 subtiles (1 KiB), content XOR-swizzled
// (byte bit5 ^= row bit3); staged via global_load_lds (1 subtile per instr per wave)
// with inverse-swizzled per-lane GLOBAL source; ds_read applies the same XOR.
// Schedule per K-tile: compute(buf c) ; barrier ; issue stage(t+2 -> buf c) ;
// vmcnt(NSW) [t+1 landed, t+2 stays in flight] ; barrier.  Never drains in main loop.
template <int BM, typename OT>
__global__ __launch_bounds__(512) void k_gemm2(const bf16* __restrict__ A, const bf16* __restrict__ Bt,
                                               OT* __restrict__ C, int N, int Kd) {
  constexpr int NA = (BM / 16) * 2;   // A subtiles per K-tile
  constexpr int NB = 16;              // B subtiles (BN=128 x BK=64)
  constexpr int NST = NA + NB;
  constexpr int NSW = NST / 8;        // stage instrs per wave per K-tile (6 or 4)
  constexpr int WM = BM / 4;          // wave rows (waves 4M x 2N)
  constexpr int RG = WM / 16;         // A row-groups per wave
  __shared__ __align__(16) bf16 sAB[2][NST * 512];
  const int t = threadIdx.x, w = t >> 6, l = t & 63;
  const int lr = l & 15, lk = l >> 4;
  const int gx = gridDim.x;
  const int nwg = gx * gridDim.y;
  const int flat = blockIdx.y * gx + blockIdx.x;
  const int vid = (flat & 7) * (nwg >> 3) + (flat >> 3);  // XCD swizzle (nwg % 8 == 0)
  const int m0 = (vid % gx) * BM, n0 = (vid / gx) * 128;
  const int wm = w >> 1, wn = w & 1;
  const int srow = l >> 2;                             // staging: row within subtile
  const int lchunk = (l & 3) ^ (((l >> 5) & 1) << 1);  // logical 16B chunk (swizzle inverse)
  const int rdoff = lr * 64 + ((lk * 16) ^ ((lr >> 3) << 5));  // swizzled read offset
  const int nkt = Kd >> 6;
  char* lds = (char*)sAB;

  auto stage = [&](int kt, int buf) {
    const int k0 = kt << 6;
#pragma unroll
    for (int u = 0; u < NSW; ++u) {
      const int s = w * NSW + u;
      const bf16* src;
      if (s < NA)
        src = A + (size_t)(m0 + (s >> 1) * 16 + srow) * Kd + k0 + (s & 1) * 32 + lchunk * 8;
      else
        src = Bt + (size_t)(n0 + ((s - NA) >> 1) * 16 + srow) * Kd + k0 + ((s - NA) & 1) * 32 + lchunk * 8;
      gload_lds16(src, lds + buf * (NST * 1024) + s * 1024);
    }
  };

  f32x4 acc[RG][4] = {};
  stage(0, 0);
  stage(1, 1);
  if constexpr (NSW == 6) S_WAITCNT_VM(6); else S_WAITCNT_VM(4);
  __builtin_amdgcn_s_barrier();  // tile 0 resident everywhere; tile 1 in flight
  int c = 0;
  for (int kt = 0; kt < nkt; ++kt) {
    __builtin_amdgcn_sched_barrier(0);
    const char* base = lds + c * (NST * 1024);
    bf16x8 af[RG][2], bfr[4][2];
#pragma unroll
    for (int i = 0; i < RG; ++i)
#pragma unroll
      for (int kk = 0; kk < 2; ++kk)
        af[i][kk] = *reinterpret_cast<const bf16x8*>(base + ((wm * RG + i) * 2 + kk) * 1024 + rdoff);
#pragma unroll
    for (int j = 0; j < 4; ++j)
#pragma unroll
      for (int kk = 0; kk < 2; ++kk)
        bfr[j][kk] = *reinterpret_cast<const bf16x8*>(base + (NA + (wn * 4 + j) * 2 + kk) * 1024 + rdoff);
    __builtin_amdgcn_s_setprio(1);
#pragma unroll
    for (int i = 0; i < RG; ++i)
#pragma unroll
      for (int j = 0; j < 4; ++j) {
        acc[i][j] = __builtin_amdgcn_mfma_f32_16x16x32_bf16(af[i][0], bfr[j][0], acc[i][j], 0, 0, 0);
        acc[i][j] = __builtin_amdgcn_mfma_f32_16x16x32_bf16(af[i][1], bfr[j][1], acc[i][j], 0, 0, 0);
      }
    __builtin_amdgcn_s_setprio(0);
    __builtin_amdgcn_sched_barrier(0);
    asm volatile("" ::: "memory");
    __builtin_amdgcn_s_barrier();  // all reads of buf c complete
    if (kt + 2 < nkt) stage(kt + 2, c);  // overwrite freed buf; writes land later
    if (kt + 1 < nkt) {
      if (kt + 2 < nkt) {
        if constexpr (NSW == 6) S_WAITCNT_VM(6); else S_WAITCNT_VM(4);
      } else {
        S_WAITCNT_VM(0);
      }
      asm volatile("" ::: "memory");
      __builtin_amdgcn_s_barrier();  // all waves' tile kt+1 writes landed
    }
    c ^= 1;
  }
#pragma unroll
  for (int i = 0; i < RG; ++i)
#pragma unroll
    for (int j = 0; j < 4; ++j)
#pragma unroll
      for (int r = 0; r < 4; ++r) {
        int row = m0 + wm * WM + i * 16 + lk * 4 + r;
        int col = n0 + wn * 64 + j * 16 + lr;
        if constexpr (sizeof(OT) == 4)
          C[(size_t)row * N + col] = acc[i][j][r];
        else
          C[(size_t)row * N + col] = (bf16)acc[i][j][r];
      }
}

// ---------------- RoPE in place (optionally folds score scale into Q) ----------------
__global__ void k_rope(bf16* __restrict__ X, const float* __restrict__ cs, const float* __restrict__ sn,
                       int nh, int rowstride, float scale, int total) {
  int idx = blockIdx.x * blockDim.x + threadIdx.x;
  if (idx >= total) return;
  int d = idx & 63;
  int th = idx >> 6;
  int h = th % nh;
  int tok = th / nh;
  size_t base = (size_t)tok * rowstride + h * 128;
  float c = cs[tok * 128 + d], s = sn[tok * 128 + d];
  float x1 = (float)X[base + d];
  float x2 = (float)X[base + d + 64];
  X[base + d] = (bf16)((x1 * c - x2 * s) * scale);
  X[base + d + 64] = (bf16)((x2 * c + x1 * s) * scale);
}

// ---------------- causal flash attention, GQA 4:1, bf16 MFMA (round-5 verified) ------
__global__ __launch_bounds__(256) void k_attn(const bf16* __restrict__ Q, const bf16* __restrict__ KV,
                                              const bf16* __restrict__ Vt, bf16* __restrict__ O) {
  constexpr int S = 2048, NH = 16, HD = 128, QSTR = NH * HD, KVSTR = 1024;
  __shared__ __align__(16) bf16 sK[2][64 * 128];
  __shared__ __align__(16) bf16 sV[2][128 * 64];
  __shared__ __align__(16) bf16 sP[4][16][72];
  const int bid = blockIdx.x;
  const int vid = (bid & 7) * 64 + (bid >> 3);  // XCD swizzle: 64 consecutive per XCD
  const int p = vid & 15, bh = vid >> 4;
  const int h = bh & 15, b = bh >> 4;
  const int t = threadIdx.x, w = t >> 6, l = t & 63;
  const int lr = l & 15, lk = l >> 4;
  const int kvh = h >> 2;
  const int swz = (lr & 7) << 4;

  const char* kbase = (const char*)(KV + (size_t)b * S * KVSTR + kvh * HD);
  const int krow_l = w * 16 + (l >> 4);
  const int kcol_l = (l & 15) << 4;
  const char* vtbase = (const char*)(Vt + (size_t)(b * 4 + kvh) * HD * S);
  const int vrow_l = w * 32 + (l >> 3);
  const int vcol_l = (l & 7) << 4;
  char* sKb = (char*)sK;
  char* sVb = (char*)sV;
  auto stage = [&](int kvb, int buf) {
#pragma unroll
    for (int c = 0; c < 4; ++c) {
      const int krow = krow_l + c * 4;
      gload_lds16(kbase + (size_t)(kvb + krow) * 2048 + (kcol_l ^ ((krow & 7) << 4)),
                  sKb + buf * 16384 + (w * 4 + c) * 1024);
      const int vrow = vrow_l + c * 8;
      gload_lds16(vtbase + (size_t)vrow * (S * 2) + kvb * 2 + (vcol_l ^ ((vrow & 7) << 4)),
                  sVb + buf * 16384 + (w * 4 + c) * 1024);
    }
  };

  for (int seg = 0; seg < 2; ++seg) {
    const int qtl = seg ? (31 - p) : p;
    const int qw = qtl * 64 + w * 16;
    const int ntiles = qtl + 1;
    int cur = 0;
    stage(0, 0);
    const bf16* Qp = Q + (size_t)(b * S + qw + lr) * QSTR + h * HD + lk * 8;
    bf16x8 qf[4];
#pragma unroll
    for (int i = 0; i < 4; ++i) qf[i] = *reinterpret_cast<const bf16x8*>(Qp + i * 32);
    f32x4 oacc[8] = {};
    float mrow[4] = {-3e38f, -3e38f, -3e38f, -3e38f};
    float lsum[4] = {0.f, 0.f, 0.f, 0.f};
    __syncthreads();
    for (int tt = 0; tt < ntiles; ++tt) {
      const int kvb = tt * 64;
      if (tt + 1 < ntiles) stage(kvb + 64, cur ^ 1);
      const char* sKc = sKb + cur * 16384;
      const char* sVc = sVb + cur * 16384;
      float pm[4][4];
#pragma unroll
      for (int c = 0; c < 4; ++c) {
        f32x4 s4 = {};
#pragma unroll
        for (int kf = 0; kf < 4; ++kf) {
          bf16x8 kf8 = *reinterpret_cast<const bf16x8*>(
              sKc + (c * 16 + lr) * 256 + (((kf * 64) + (lk << 4)) ^ swz));
          s4 = __builtin_amdgcn_mfma_f32_16x16x32_bf16(qf[kf], kf8, s4, 0, 0, 0);
        }
#pragma unroll
        for (int r = 0; r < 4; ++r) pm[c][r] = s4[r];
      }
      if (tt == ntiles - 1) {
#pragma unroll
        for (int c = 0; c < 4; ++c) {
          const int col = kvb + c * 16 + lr;
#pragma unroll
          for (int r = 0; r < 4; ++r)
            if (col > qw + lk * 4 + r) pm[c][r] = -3e38f;
        }
      }
      float pmax[4];
#pragma unroll
      for (int r = 0; r < 4; ++r)
        pmax[r] = fmaxf(fmaxf(pm[0][r], pm[1][r]), fmaxf(pm[2][r], pm[3][r]));
      bool hi = (pmax[0] > mrow[0] + 8.f) | (pmax[1] > mrow[1] + 8.f) |
                (pmax[2] > mrow[2] + 8.f) | (pmax[3] > mrow[3] + 8.f);
      if (__any(hi)) {
        float mx[4];
#pragma unroll
        for (int r = 0; r < 4; ++r) mx[r] = pmax[r];
#pragma unroll
        for (int off = 1; off < 16; off <<= 1)
#pragma unroll
          for (int r = 0; r < 4; ++r) mx[r] = fmaxf(mx[r], __shfl_xor(mx[r], off));
#pragma unroll
        for (int r = 0; r < 4; ++r) {
          float mn = fmaxf(mrow[r], mx[r]);
          float fac = fexp2(mrow[r] - mn);
          mrow[r] = mn;
          lsum[r] *= fac;
#pragma unroll
          for (int ch = 0; ch < 8; ++ch) oacc[ch][r] *= fac;
        }
      }
#pragma unroll
      for (int c = 0; c < 4; ++c)
#pragma unroll
        for (int r = 0; r < 4; ++r) pm[c][r] = fexp2(pm[c][r] - mrow[r]);
#pragma unroll
      for (int r = 0; r < 4; ++r)
        lsum[r] += (pm[0][r] + pm[1][r]) + (pm[2][r] + pm[3][r]);
#pragma unroll
      for (int c = 0; c < 4; ++c)
#pragma unroll
        for (int r = 0; r < 4; ++r) sP[w][lk * 4 + r][c * 16 + lr] = (bf16)pm[c][r];
      bf16x8 pf0 = *reinterpret_cast<const bf16x8*>(&sP[w][lr][lk * 8]);
      bf16x8 pf1 = *reinterpret_cast<const bf16x8*>(&sP[w][lr][32 + lk * 8]);
#pragma unroll
      for (int ch = 0; ch < 8; ++ch) {
        bf16x8 vf0 = *reinterpret_cast<const bf16x8*>(
            sVc + (ch * 16 + lr) * 128 + ((lk << 4) ^ swz));
        oacc[ch] = __builtin_amdgcn_mfma_f32_16x16x32_bf16(pf0, vf0, oacc[ch], 0, 0, 0);
        bf16x8 vf1 = *reinterpret_cast<const bf16x8*>(
            sVc + (ch * 16 + lr) * 128 + ((64 + (lk << 4)) ^ swz));
        oacc[ch] = __builtin_amdgcn_mfma_f32_16x16x32_bf16(pf1, vf1, oacc[ch], 0, 0, 0);
      }
      __syncthreads();
      cur ^= 1;
    }
#pragma unroll
    for (int off = 1; off < 16; off <<= 1)
#pragma unroll
      for (int r = 0; r < 4; ++r) lsum[r] += __shfl_xor(lsum[r], off);
    float inv[4];
#pragma unroll
    for (int r = 0; r < 4; ++r) inv[r] = 1.0f / lsum[r];
    bf16* Op = O + (size_t)(b * S + qw) * QSTR + h * HD;
#pragma unroll
    for (int ch = 0; ch < 8; ++ch)
#pragma unroll
      for (int r = 0; r < 4; ++r)
        Op[(size_t)(lk * 4 + r) * QSTR + ch * 16 + lr] = (bf16)(oacc[ch][r] * inv[r]);
  }
}

extern "C" void kernel_launch(void* const* d_in, const int* in_sizes, int n_in,
                              void* d_out, int out_size, void* d_ws, size_t ws_size,
                              hipStream_t stream) {
  const float* hs = (const float*)d_in[0];
  // d_in[1] = attention_mask: pure causal, applied analytically
  const float* cosb = (const float*)d_in[2];
  const float* sinb = (const float*)d_in[3];
  const float* Wq = (const float*)d_in[4];
  const float* Wk = (const float*)d_in[5];
  const float* Wv = (const float*)d_in[6];
  const float* Wo = (const float*)d_in[7];
  float* out = (float*)d_out;

  constexpr int B = 2, S = 2048, H = 2048, NH = 16, NKV = 4, HD = 128;
  constexpr int T = B * S;
  constexpr size_t MB = 1024 * 1024;

  // Workspace plan (d_ws 24 MiB; Q/KV/Vt staged inside d_out = 32 MiB):
  //   d_ws[ 0:16M) : Xb (bf16 X), reused as Ob after QKV projections
  //   d_ws[16:24M) : transposed-weight slot: Wqt -> Wkvt -> Wot (serial lifetimes)
  //   d_out[ 0:16M): Qb   d_out[16:24M): KVb   d_out[24:28M): Vt
  const size_t ws_need = 24 * MB;
  if (ws_size < ws_need) {
    k_diag<<<1, 64, 0, stream>>>(out, 1000.0f + (float)(ws_size / MB));
    return;
  }
  bf16* Xb = (bf16*)d_ws;
  bf16* Wt = (bf16*)((char*)d_ws + 16 * MB);
  bf16* Ob = Xb;
  bf16* Qb = (bf16*)d_out;
  bf16* KVb = (bf16*)((char*)d_out + 16 * MB);
  bf16* Vtb = (bf16*)((char*)d_out + 24 * MB);

  k_cvt_bf16<<<T * H / 4 / 256, 256, 0, stream>>>(hs, Xb, T * H / 4);

  // Q projection (grid 256 blocks, full CU fill)
  k_transpose_w<<<dim3(H / 32, NH * HD / 32), 256, 0, stream>>>(Wq, Wt, H, NH * HD);
  k_gemm2<256, bf16><<<dim3(16, 16), 512, 0, stream>>>(Xb, Wt, Qb, NH * HD, H);

  // K|V fused projection (N rows 0..511 = K, 512..1023 = V; grid 256)
  k_transpose_w<<<dim3(H / 32, NKV * HD / 32), 256, 0, stream>>>(Wk, Wt, H, NKV * HD);
  k_transpose_w<<<dim3(H / 32, NKV * HD / 32), 256, 0, stream>>>(Wv, Wt + (size_t)(NKV * HD) * H, H, NKV * HD);
  k_gemm2<128, bf16><<<dim3(32, 8), 512, 0, stream>>>(Xb, Wt, KVb, 1024, H);

  // V -> Vt[b][kvh][HD][S] (V gets no RoPE)
  k_transpose_v<<<dim3(S / 32, HD / 32, B * NKV), 256, 0, stream>>>(KVb, Vtb);

  // RoPE; Q additionally folds log2(e)/sqrt(HD) so QK^T lands in log2 domain
  const float qscale = 0.12751743f;  // log2(e) / sqrt(128)
  k_rope<<<(T * NH * 64) / 256, 256, 0, stream>>>(Qb, cosb, sinb, NH, NH * HD, qscale, T * NH * 64);
  k_rope<<<(T * NKV * 64) / 256, 256, 0, stream>>>(KVb, cosb, sinb, NKV, 1024, 1.0f, T * NKV * 64);

  // Attention: reads Q/K/Vt from d_out, writes Ob into d_ws
  k_attn<<<512, 256, 0, stream>>>(Qb, KVb, Vtb, Ob);

  // O projection: reads only d_ws, writes all of d_out (grid 256)
  k_transpose_w<<<dim3(H / 32, H / 32), 256, 0, stream>>>(Wo, Wt, H, H);
  k_gemm2<256, float><<<dim3(16, 16), 512, 0, stream>>>(Ob, Wt, out, H, H);
}